// Round 1
// baseline (5672.719 us; speedup 1.0000x reference)
//
#include <hip/hip_runtime.h>
#include <cstdint>
#include <cstddef>

// ---------------------------------------------------------------------------
// GCN(1 layer, sym-norm w/ self loops) -> LSTM(1 layer, T=9) -> FC, eval mode
// All fp32 vector math this round (correctness baseline).
// ---------------------------------------------------------------------------

constexpr int N    = 50000;
constexpr int E    = 1600000;
constexpr int T    = 9;
constexpr int H    = 128;    // F_IN == H == 128
constexpr int G    = 512;    // 4*H (gates i,f,g,o)
constexpr int OUTD = 32;

constexpr int SCAN_CH = 512;
constexpr int NCH = (N + SCAN_CH - 1) / SCAN_CH;   // 98

// ---------------- degree / CSR build ----------------

__global__ void k_count(const int* __restrict__ col, int* __restrict__ cnt) {
  int e = blockIdx.x * 256 + threadIdx.x;
  if (e < E) atomicAdd(&cnt[col[e]], 1);
}

__global__ void k_dinv(const int* __restrict__ cnt, float* __restrict__ dinv) {
  int v = blockIdx.x * 256 + threadIdx.x;
  if (v < N) dinv[v] = rsqrtf((float)cnt[v] + 1.0f);   // +1 self loop
}

__global__ void k_chunk_sum(const int* __restrict__ cnt, int* __restrict__ csum) {
  __shared__ int sp[SCAN_CH / 64];
  int i = blockIdx.x * SCAN_CH + threadIdx.x;
  int v = (i < N) ? cnt[i] : 0;
  for (int off = 32; off > 0; off >>= 1) v += __shfl_down(v, off, 64);
  if ((threadIdx.x & 63) == 0) sp[threadIdx.x >> 6] = v;
  __syncthreads();
  if (threadIdx.x == 0) {
    int s = 0;
    #pragma unroll
    for (int w = 0; w < SCAN_CH / 64; ++w) s += sp[w];
    csum[blockIdx.x] = s;
  }
}

__global__ void k_chunk_scan(const int* __restrict__ csum, int* __restrict__ coff) {
  if (blockIdx.x == 0 && threadIdx.x == 0) {
    int run = 0;
    for (int b = 0; b < NCH; ++b) { coff[b] = run; run += csum[b]; }
    coff[NCH] = run;
  }
}

__global__ void k_scan_final(const int* __restrict__ cnt, const int* __restrict__ coff,
                             int* __restrict__ offv) {
  __shared__ int s[SCAN_CH];
  int tid = threadIdx.x;
  int i = blockIdx.x * SCAN_CH + tid;
  int v = (i < N) ? cnt[i] : 0;
  s[tid] = v;
  __syncthreads();
  for (int st = 1; st < SCAN_CH; st <<= 1) {
    int tv = (tid >= st) ? s[tid - st] : 0;
    __syncthreads();
    s[tid] += tv;
    __syncthreads();
  }
  if (i < N) offv[i] = coff[blockIdx.x] + s[tid] - v;   // exclusive
  if (blockIdx.x == 0 && tid == 0) offv[N] = coff[NCH];
}

__global__ void k_fill(const int* __restrict__ row, const int* __restrict__ col,
                       const float* __restrict__ dinv, const int* __restrict__ offv,
                       int* __restrict__ cursor, int* __restrict__ csr_src,
                       float* __restrict__ csr_norm) {
  int e = blockIdx.x * 256 + threadIdx.x;
  if (e >= E) return;
  int r = row[e], c = col[e];
  int p = atomicAdd(&cursor[c], 1);
  int idx = offv[c] + p;
  csr_src[idx]  = r;
  csr_norm[idx] = dinv[r] * dinv[c];
}

// transpose+concat LSTM weights: wcatT[k][j], k<128 -> W_ih[j][k], else W_hh[j][k-128]
__global__ void k_wcat(const float* __restrict__ Wih, const float* __restrict__ Whh,
                       float* __restrict__ wcatT) {
  int idx = blockIdx.x * 256 + threadIdx.x;   // 256*512
  if (idx >= 256 * G) return;
  int k = idx / G, j = idx % G;
  wcatT[idx] = (k < H) ? Wih[j * H + k] : Whh[j * H + (k - H)];
}

// ---------------- GCN GEMM: xw = x_t @ W_gcn ----------------
// block: 256 thr, 64 rows, 128 cols; A staged transposed in LDS (pad 68),
// B rows streamed from L2 as float4.
__global__ __launch_bounds__(256, 4) void k_gemm_gcn(const float* __restrict__ A,
                                                     const float* __restrict__ B,
                                                     float* __restrict__ outp) {
  __shared__ float asT[128][68];
  int tid = threadIdx.x;
  int n0 = blockIdx.x * 64;
  for (int i = 0; i < 32; ++i) {
    int idx = i * 256 + tid;
    int r = idx >> 7, k = idx & 127;
    asT[k][r] = (n0 + r < N) ? A[(size_t)(n0 + r) * H + k] : 0.0f;
  }
  __syncthreads();
  int cg = tid & 31, rg = tid >> 5;
  int c0 = cg * 4, r0 = rg * 8;
  float acc[8][4];
  #pragma unroll
  for (int i = 0; i < 8; ++i) { acc[i][0]=0.f; acc[i][1]=0.f; acc[i][2]=0.f; acc[i][3]=0.f; }
  #pragma unroll 2
  for (int k = 0; k < 128; ++k) {
    float4 b  = *(const float4*)&B[(size_t)k * H + c0];
    float4 a0 = *(const float4*)&asT[k][r0];
    float4 a1 = *(const float4*)&asT[k][r0 + 4];
    float ar[8] = {a0.x,a0.y,a0.z,a0.w,a1.x,a1.y,a1.z,a1.w};
    #pragma unroll
    for (int i = 0; i < 8; ++i) {
      acc[i][0] = fmaf(ar[i], b.x, acc[i][0]);
      acc[i][1] = fmaf(ar[i], b.y, acc[i][1]);
      acc[i][2] = fmaf(ar[i], b.z, acc[i][2]);
      acc[i][3] = fmaf(ar[i], b.w, acc[i][3]);
    }
  }
  #pragma unroll
  for (int i = 0; i < 8; ++i) {
    int n = n0 + r0 + i;
    if (n < N)
      *(float4*)&outp[(size_t)n * H + c0] =
          make_float4(acc[i][0], acc[i][1], acc[i][2], acc[i][3]);
  }
}

// ---------------- aggregation: emb_t[v] = relu(sum_in xw[src]*norm + dinv^2*xw[v] + b) ----
__global__ __launch_bounds__(256) void k_agg(const float* __restrict__ xw,
                                             const int* __restrict__ offv,
                                             const int* __restrict__ csr_src,
                                             const float* __restrict__ csr_norm,
                                             const float* __restrict__ dinv,
                                             const float* __restrict__ bg,
                                             float* __restrict__ embt) {
  int wid = threadIdx.x >> 6, lane = threadIdx.x & 63;
  int v = blockIdx.x * 4 + wid;          // N % 4 == 0
  float dv = dinv[v];
  float w = dv * dv;
  float2 xs = *(const float2*)&xw[(size_t)v * H + lane * 2];
  float accx = xs.x * w, accy = xs.y * w;
  int e0 = offv[v], e1 = offv[v + 1];
  int e = e0;
  for (; e + 1 < e1; e += 2) {
    int   s0 = csr_src[e],   s1 = csr_src[e + 1];
    float m0 = csr_norm[e],  m1 = csr_norm[e + 1];
    float2 x0 = *(const float2*)&xw[(size_t)s0 * H + lane * 2];
    float2 x1 = *(const float2*)&xw[(size_t)s1 * H + lane * 2];
    accx = fmaf(x0.x, m0, accx); accy = fmaf(x0.y, m0, accy);
    accx = fmaf(x1.x, m1, accx); accy = fmaf(x1.y, m1, accy);
  }
  for (; e < e1; ++e) {
    int s = csr_src[e]; float m = csr_norm[e];
    float2 x0 = *(const float2*)&xw[(size_t)s * H + lane * 2];
    accx = fmaf(x0.x, m, accx); accy = fmaf(x0.y, m, accy);
  }
  float2 bb = *(const float2*)&bg[lane * 2];
  float2 o;
  o.x = fmaxf(accx + bb.x, 0.f);
  o.y = fmaxf(accy + bb.y, 0.f);
  *(float2*)&embt[(size_t)v * H + lane * 2] = o;
}

// ---------------- gates GEMM: gates = [emb_t, h] @ wcatT + (b_ih+b_hh) ----------------
// grid (rows/64, 4); block 256; K processed in two 128 halves to keep LDS at 34.8KB.
__global__ __launch_bounds__(256, 4) void k_gates(const float* __restrict__ Aemb,
                                                  const float* __restrict__ Ah,
                                                  const float* __restrict__ BT,
                                                  const float* __restrict__ bih,
                                                  const float* __restrict__ bhh,
                                                  float* __restrict__ gates) {
  __shared__ float asT[128][68];
  int tid = threadIdx.x;
  int n0 = blockIdx.x * 64;
  int cg = tid & 31, rg = tid >> 5;
  int j0 = blockIdx.y * 128 + cg * 4, r0 = rg * 8;
  float acc[8][4];
  #pragma unroll
  for (int i = 0; i < 8; ++i) { acc[i][0]=0.f; acc[i][1]=0.f; acc[i][2]=0.f; acc[i][3]=0.f; }

  for (int half = 0; half < 2; ++half) {
    if (half) __syncthreads();           // all reads of previous tile done
    const float* src = half ? Ah : Aemb;
    for (int i = 0; i < 32; ++i) {
      int idx = i * 256 + tid;
      int r = idx >> 7, k = idx & 127;
      asT[k][r] = (n0 + r < N) ? src[(size_t)(n0 + r) * H + k] : 0.0f;
    }
    __syncthreads();
    const float* Bh = BT + (size_t)half * 128 * G;
    #pragma unroll 2
    for (int k = 0; k < 128; ++k) {
      float4 b  = *(const float4*)&Bh[(size_t)k * G + j0];
      float4 a0 = *(const float4*)&asT[k][r0];
      float4 a1 = *(const float4*)&asT[k][r0 + 4];
      float ar[8] = {a0.x,a0.y,a0.z,a0.w,a1.x,a1.y,a1.z,a1.w};
      #pragma unroll
      for (int i = 0; i < 8; ++i) {
        acc[i][0] = fmaf(ar[i], b.x, acc[i][0]);
        acc[i][1] = fmaf(ar[i], b.y, acc[i][1]);
        acc[i][2] = fmaf(ar[i], b.z, acc[i][2]);
        acc[i][3] = fmaf(ar[i], b.w, acc[i][3]);
      }
    }
  }
  float4 bb;
  bb.x = bih[j0 + 0] + bhh[j0 + 0];
  bb.y = bih[j0 + 1] + bhh[j0 + 1];
  bb.z = bih[j0 + 2] + bhh[j0 + 2];
  bb.w = bih[j0 + 3] + bhh[j0 + 3];
  #pragma unroll
  for (int i = 0; i < 8; ++i) {
    int n = n0 + r0 + i;
    if (n < N)
      *(float4*)&gates[(size_t)n * G + j0] =
          make_float4(acc[i][0]+bb.x, acc[i][1]+bb.y, acc[i][2]+bb.z, acc[i][3]+bb.w);
  }
}

// ---------------- LSTM cell (elementwise) ----------------
__global__ void k_cell(const float* __restrict__ gates, float* __restrict__ c,
                       float* __restrict__ h) {
  int idx = blockIdx.x * 256 + threadIdx.x;     // exactly N*H threads
  int n = idx >> 7, ch = idx & 127;
  const float* g = &gates[(size_t)n * G];
  float gi = g[ch], gf = g[128 + ch], gg = g[256 + ch], go = g[384 + ch];
  float si = 1.f / (1.f + expf(-gi));
  float sf = 1.f / (1.f + expf(-gf));
  float so = 1.f / (1.f + expf(-go));
  float tg = tanhf(gg);
  float cn = sf * c[idx] + si * tg;
  c[idx] = cn;
  h[idx] = so * tanhf(cn);
}

// ---------------- FC per step: out[n][t][:] = h[n] @ W_fc^T + b_fc ----------------
__global__ __launch_bounds__(256, 3) void k_fc(const float* __restrict__ h,
                                               const float* __restrict__ Wfc,
                                               const float* __restrict__ bfc,
                                               float* __restrict__ outp, int t) {
  __shared__ float hsT[128][68];
  __shared__ float wT[128][36];
  int tid = threadIdx.x;
  int n0 = blockIdx.x * 64;
  for (int i = 0; i < 32; ++i) {
    int idx = i * 256 + tid;
    int r = idx >> 7, k = idx & 127;
    hsT[k][r] = (n0 + r < N) ? h[(size_t)(n0 + r) * H + k] : 0.0f;
  }
  for (int i = 0; i < 16; ++i) {
    int idx = i * 256 + tid;          // 4096 = 32*128
    int oc = idx >> 7, k = idx & 127;
    wT[k][oc] = Wfc[idx];
  }
  __syncthreads();
  int og = tid & 15, rg = tid >> 4;   // 16 oc-groups x 16 row-groups
  int oc0 = og * 2, r0 = rg * 4;
  float acc[4][2] = {};
  #pragma unroll 2
  for (int k = 0; k < 128; ++k) {
    float4 a = *(const float4*)&hsT[k][r0];
    float2 w = *(const float2*)&wT[k][oc0];
    float ar[4] = {a.x, a.y, a.z, a.w};
    #pragma unroll
    for (int i = 0; i < 4; ++i) {
      acc[i][0] = fmaf(ar[i], w.x, acc[i][0]);
      acc[i][1] = fmaf(ar[i], w.y, acc[i][1]);
    }
  }
  float b0 = bfc[oc0], b1 = bfc[oc0 + 1];
  #pragma unroll
  for (int i = 0; i < 4; ++i) {
    int n = n0 + r0 + i;
    if (n < N) {
      size_t ob = ((size_t)n * T + t) * OUTD + oc0;
      outp[ob]     = acc[i][0] + b0;
      outp[ob + 1] = acc[i][1] + b1;
    }
  }
}

// ---------------------------------------------------------------------------

extern "C" void kernel_launch(void* const* d_in, const int* in_sizes, int n_in,
                              void* d_out, int out_size, void* d_ws, size_t ws_size,
                              hipStream_t stream) {
  const float* x_seq = (const float*)d_in[0];
  const int*   eidx  = (const int*)d_in[1];
  const int*   erow  = eidx;          // sources
  const int*   ecol  = eidx + E;      // targets
  const float* W_gcn = (const float*)d_in[2];
  const float* b_gcn = (const float*)d_in[3];
  const float* W_ih  = (const float*)d_in[4];
  const float* W_hh  = (const float*)d_in[5];
  const float* b_ih  = (const float*)d_in[6];
  const float* b_hh  = (const float*)d_in[7];
  const float* W_fc  = (const float*)d_in[8];
  const float* b_fc  = (const float*)d_in[9];
  float* outp = (float*)d_out;

  char* base = (char*)d_ws;
  size_t o = 0;
  auto alloc = [&](size_t bytes) -> void* {
    void* p = base + o;
    o += (bytes + 255) & ~(size_t)255;
    return p;
  };
  int*   cnt      = (int*)  alloc((size_t)N * 4);
  int*   cursor   = (int*)  alloc((size_t)N * 4);
  int*   offv     = (int*)  alloc((size_t)(N + 1) * 4);
  int*   csum     = (int*)  alloc((size_t)(NCH + 1) * 4);
  int*   coff     = (int*)  alloc((size_t)(NCH + 1) * 4);
  float* dinv     = (float*)alloc((size_t)N * 4);
  int*   csr_src  = (int*)  alloc((size_t)E * 4);
  float* csr_norm = (float*)alloc((size_t)E * 4);
  float* wcatT    = (float*)alloc((size_t)256 * G * 4);
  float* xw       = (float*)alloc((size_t)N * H * 4);
  float* embt     = (float*)alloc((size_t)N * H * 4);
  float* gates    = (float*)alloc((size_t)N * G * 4);
  float* hbuf     = (float*)alloc((size_t)N * H * 4);
  float* cbuf     = (float*)alloc((size_t)N * H * 4);
  (void)ws_size; (void)in_sizes; (void)n_in; (void)out_size;

  hipMemsetAsync(cnt,    0, (size_t)N * 4, stream);
  hipMemsetAsync(cursor, 0, (size_t)N * 4, stream);
  hipMemsetAsync(hbuf,   0, (size_t)N * H * 4, stream);
  hipMemsetAsync(cbuf,   0, (size_t)N * H * 4, stream);

  k_count<<<E / 256, 256, 0, stream>>>(ecol, cnt);
  k_dinv<<<(N + 255) / 256, 256, 0, stream>>>(cnt, dinv);
  k_chunk_sum<<<NCH, SCAN_CH, 0, stream>>>(cnt, csum);
  k_chunk_scan<<<1, 64, 0, stream>>>(csum, coff);
  k_scan_final<<<NCH, SCAN_CH, 0, stream>>>(cnt, coff, offv);
  k_fill<<<E / 256, 256, 0, stream>>>(erow, ecol, dinv, offv, cursor, csr_src, csr_norm);
  k_wcat<<<(256 * G) / 256, 256, 0, stream>>>(W_ih, W_hh, wcatT);

  int rblocks = (N + 63) / 64;
  for (int t = 0; t < T; ++t) {
    const float* xt = x_seq + (size_t)t * N * H;
    k_gemm_gcn<<<rblocks, 256, 0, stream>>>(xt, W_gcn, xw);
    k_agg<<<N / 4, 256, 0, stream>>>(xw, offv, csr_src, csr_norm, dinv, b_gcn, embt);
    k_gates<<<dim3(rblocks, 4), 256, 0, stream>>>(embt, hbuf, wcatT, b_ih, b_hh, gates);
    k_cell<<<(N * H) / 256, 256, 0, stream>>>(gates, cbuf, hbuf);
    k_fc<<<rblocks, 256, 0, stream>>>(hbuf, W_fc, b_fc, outp, t);
  }
}

// Round 2
// 3064.903 us; speedup vs baseline: 1.8509x; 1.8509x over previous
//
#include <hip/hip_runtime.h>
#include <cstdint>
#include <cstddef>

// ---------------------------------------------------------------------------
// GCN(1 layer, sym-norm w/ self loops) -> LSTM(1 layer, T=9) -> FC, eval mode
// Round 2: GEMMs moved to split-bf16 MFMA (hi+lo decomposition, 3 mfma/pair).
// ---------------------------------------------------------------------------

constexpr int N    = 50000;
constexpr int NP   = 50048;  // padded to 128-row blocks (391*128)
constexpr int E    = 1600000;
constexpr int T    = 9;
constexpr int H    = 128;    // F_IN == H == 128
constexpr int G    = 512;    // 4*H (gates i,f,g,o)
constexpr int OUTD = 32;

constexpr int SCAN_CH = 512;
constexpr int NCH = (N + SCAN_CH - 1) / SCAN_CH;   // 98

typedef __attribute__((ext_vector_type(8))) short bf16x8;
typedef __attribute__((ext_vector_type(4))) float f32x4;
typedef unsigned short u16;

__device__ __forceinline__ u16 f2bf(float f) {        // RNE f32 -> bf16 bits
  unsigned u = __builtin_bit_cast(unsigned, f);
  u += 0x7fffu + ((u >> 16) & 1u);
  return (u16)(u >> 16);
}
__device__ __forceinline__ float bf2f(u16 h) {
  unsigned u = ((unsigned)h) << 16;
  return __builtin_bit_cast(float, u);
}

// ---------------- degree / CSR build ----------------

__global__ void k_count(const int* __restrict__ col, int* __restrict__ cnt) {
  int e = blockIdx.x * 256 + threadIdx.x;
  if (e < E) atomicAdd(&cnt[col[e]], 1);
}

__global__ void k_dinv(const int* __restrict__ cnt, float* __restrict__ dinv) {
  int v = blockIdx.x * 256 + threadIdx.x;
  if (v < N) dinv[v] = rsqrtf((float)cnt[v] + 1.0f);   // +1 self loop
}

__global__ void k_chunk_sum(const int* __restrict__ cnt, int* __restrict__ csum) {
  __shared__ int sp[SCAN_CH / 64];
  int i = blockIdx.x * SCAN_CH + threadIdx.x;
  int v = (i < N) ? cnt[i] : 0;
  for (int off = 32; off > 0; off >>= 1) v += __shfl_down(v, off, 64);
  if ((threadIdx.x & 63) == 0) sp[threadIdx.x >> 6] = v;
  __syncthreads();
  if (threadIdx.x == 0) {
    int s = 0;
    #pragma unroll
    for (int w = 0; w < SCAN_CH / 64; ++w) s += sp[w];
    csum[blockIdx.x] = s;
  }
}

__global__ void k_chunk_scan(const int* __restrict__ csum, int* __restrict__ coff) {
  if (blockIdx.x == 0 && threadIdx.x == 0) {
    int run = 0;
    for (int b = 0; b < NCH; ++b) { coff[b] = run; run += csum[b]; }
    coff[NCH] = run;
  }
}

__global__ void k_scan_final(const int* __restrict__ cnt, const int* __restrict__ coff,
                             int* __restrict__ offv) {
  __shared__ int s[SCAN_CH];
  int tid = threadIdx.x;
  int i = blockIdx.x * SCAN_CH + tid;
  int v = (i < N) ? cnt[i] : 0;
  s[tid] = v;
  __syncthreads();
  for (int st = 1; st < SCAN_CH; st <<= 1) {
    int tv = (tid >= st) ? s[tid - st] : 0;
    __syncthreads();
    s[tid] += tv;
    __syncthreads();
  }
  if (i < N) offv[i] = coff[blockIdx.x] + s[tid] - v;   // exclusive
  if (blockIdx.x == 0 && tid == 0) offv[N] = coff[NCH];
}

__global__ void k_fill(const int* __restrict__ row, const int* __restrict__ col,
                       const float* __restrict__ dinv, const int* __restrict__ offv,
                       int* __restrict__ cursor, int* __restrict__ csr_src,
                       float* __restrict__ csr_norm) {
  int e = blockIdx.x * 256 + threadIdx.x;
  if (e >= E) return;
  int r = row[e], c = col[e];
  int p = atomicAdd(&cursor[c], 1);
  int idx = offv[c] + p;
  csr_src[idx]  = r;
  csr_norm[idx] = dinv[r] * dinv[c];
}

// ---------------- weight split/transpose (once per call) ----------------
// LSTM: Bt[j][k] (j<512, k<256): k<128 -> W_ih[j][k], else W_hh[j][k-128]
__global__ void k_wsplit_lstm(const float* __restrict__ Wih, const float* __restrict__ Whh,
                              u16* __restrict__ bhi, u16* __restrict__ blo) {
  int idx = blockIdx.x * 256 + threadIdx.x;   // 512*256
  if (idx >= G * 256) return;
  int j = idx >> 8, k = idx & 255;
  float f = (k < H) ? Wih[j * H + k] : Whh[j * H + (k - H)];
  u16 h = f2bf(f);
  u16 l = f2bf(f - bf2f(h));
  bhi[idx] = h; blo[idx] = l;
}

// GCN: Bt[j][k] = W_gcn[k][j]  (128x128)
__global__ void k_wsplit_gcn(const float* __restrict__ Wg,
                             u16* __restrict__ bhi, u16* __restrict__ blo) {
  int idx = blockIdx.x * 256 + threadIdx.x;   // 128*128
  if (idx >= H * H) return;
  int j = idx >> 7, k = idx & 127;
  float f = Wg[k * H + j];
  u16 h = f2bf(f);
  u16 l = f2bf(f - bf2f(h));
  bhi[idx] = h; blo[idx] = l;
}

// ---------------- GCN GEMM (MFMA): xw = x_t @ W_gcn ----------------
// block 256 thr = 4 waves (2x2) -> 128 rows x 128 cols; K=128 (4 kblocks).
// A fp32 read direct from x_t, split to bf16 hi/lo in-register.
__global__ __launch_bounds__(256) void k_gcn_mfma(const float* __restrict__ X,
                                                  const u16* __restrict__ Bhi,
                                                  const u16* __restrict__ Blo,
                                                  float* __restrict__ xw) {
  int lane = threadIdx.x & 63, wid = threadIdx.x >> 6;
  int wr = wid >> 1, wc = wid & 1;
  int rb = blockIdx.x * 128 + wr * 64;
  int cb = wc * 64;
  int lr = lane & 15;
  int lk = (lane >> 4) * 8;
  f32x4 acc[4][4];
  #pragma unroll
  for (int mi = 0; mi < 4; ++mi)
    #pragma unroll
    for (int ni = 0; ni < 4; ++ni) acc[mi][ni] = (f32x4)0.0f;

  #pragma unroll
  for (int kb = 0; kb < 4; ++kb) {
    int ko = kb * 32 + lk;
    bf16x8 bh[4], bl[4];
    #pragma unroll
    for (int ni = 0; ni < 4; ++ni) {
      size_t off = (size_t)(cb + ni * 16 + lr) * H + ko;
      bh[ni] = *reinterpret_cast<const bf16x8*>(Bhi + off);
      bl[ni] = *reinterpret_cast<const bf16x8*>(Blo + off);
    }
    #pragma unroll
    for (int mi = 0; mi < 4; ++mi) {
      int r = rb + mi * 16 + lr;
      r = r < N ? r : N - 1;                     // clamp (pad rows discarded)
      const float* ap = X + (size_t)r * H + ko;
      float4 a0 = *(const float4*)ap;
      float4 a1 = *(const float4*)(ap + 4);
      float fe[8] = {a0.x, a0.y, a0.z, a0.w, a1.x, a1.y, a1.z, a1.w};
      bf16x8 ah, al;
      #pragma unroll
      for (int e = 0; e < 8; ++e) {
        u16 hh = f2bf(fe[e]);
        ah[e] = (short)hh;
        al[e] = (short)f2bf(fe[e] - bf2f(hh));
      }
      #pragma unroll
      for (int ni = 0; ni < 4; ++ni) {
        acc[mi][ni] = __builtin_amdgcn_mfma_f32_16x16x32_bf16(ah, bh[ni], acc[mi][ni], 0, 0, 0);
        acc[mi][ni] = __builtin_amdgcn_mfma_f32_16x16x32_bf16(ah, bl[ni], acc[mi][ni], 0, 0, 0);
        acc[mi][ni] = __builtin_amdgcn_mfma_f32_16x16x32_bf16(al, bh[ni], acc[mi][ni], 0, 0, 0);
      }
    }
  }
  int orow = (lane >> 4) * 4;
  #pragma unroll
  for (int mi = 0; mi < 4; ++mi)
    #pragma unroll
    for (int ni = 0; ni < 4; ++ni)
      #pragma unroll
      for (int r = 0; r < 4; ++r) {
        int n = rb + mi * 16 + orow + r;
        if (n < N) xw[(size_t)n * H + cb + ni * 16 + lr] = acc[mi][ni][r];
      }
}

// ---------------- aggregation -> emb (bf16 hi/lo planes) ----------------
// emb_t[v] = relu(sum_in xw[src]*norm + dinv^2*xw[v] + b); written into
// Ahi/Alo[v][0..127] (cols 128..255 hold h, written by k_cell).
__global__ __launch_bounds__(256) void k_agg(const float* __restrict__ xw,
                                             const int* __restrict__ offv,
                                             const int* __restrict__ csr_src,
                                             const float* __restrict__ csr_norm,
                                             const float* __restrict__ dinv,
                                             const float* __restrict__ bg,
                                             u16* __restrict__ Ahi,
                                             u16* __restrict__ Alo) {
  int wid = threadIdx.x >> 6, lane = threadIdx.x & 63;
  int v = blockIdx.x * 4 + wid;          // N % 4 == 0
  float dv = dinv[v];
  float w = dv * dv;
  float2 xs = *(const float2*)&xw[(size_t)v * H + lane * 2];
  float accx = xs.x * w, accy = xs.y * w;
  int e0 = offv[v], e1 = offv[v + 1];
  int e = e0;
  for (; e + 1 < e1; e += 2) {
    int   s0 = csr_src[e],   s1 = csr_src[e + 1];
    float m0 = csr_norm[e],  m1 = csr_norm[e + 1];
    float2 x0 = *(const float2*)&xw[(size_t)s0 * H + lane * 2];
    float2 x1 = *(const float2*)&xw[(size_t)s1 * H + lane * 2];
    accx = fmaf(x0.x, m0, accx); accy = fmaf(x0.y, m0, accy);
    accx = fmaf(x1.x, m1, accx); accy = fmaf(x1.y, m1, accy);
  }
  for (; e < e1; ++e) {
    int s = csr_src[e]; float m = csr_norm[e];
    float2 x0 = *(const float2*)&xw[(size_t)s * H + lane * 2];
    accx = fmaf(x0.x, m, accx); accy = fmaf(x0.y, m, accy);
  }
  float2 bb = *(const float2*)&bg[lane * 2];
  float ox = fmaxf(accx + bb.x, 0.f);
  float oy = fmaxf(accy + bb.y, 0.f);
  u16 hx = f2bf(ox), hy = f2bf(oy);
  u16 lx = f2bf(ox - bf2f(hx)), ly = f2bf(oy - bf2f(hy));
  size_t base = (size_t)v * 256 + lane * 2;
  *(ushort2*)&Ahi[base] = make_ushort2(hx, hy);
  *(ushort2*)&Alo[base] = make_ushort2(lx, ly);
}

// ---------------- gates GEMM (MFMA): gates = [emb, h] @ Bt^T + bias ----------------
// block 256 thr = 4 waves (2x2) -> 128 rows x 128 cols; grid (NP/128, 4); K=256.
__global__ __launch_bounds__(256) void k_gates_mfma(const u16* __restrict__ Ahi,
                                                    const u16* __restrict__ Alo,
                                                    const u16* __restrict__ Bhi,
                                                    const u16* __restrict__ Blo,
                                                    const float* __restrict__ bih,
                                                    const float* __restrict__ bhh,
                                                    float* __restrict__ gates) {
  int lane = threadIdx.x & 63, wid = threadIdx.x >> 6;
  int wr = wid >> 1, wc = wid & 1;
  int rb = blockIdx.x * 128 + wr * 64;
  int cb = blockIdx.y * 128 + wc * 64;
  int lr = lane & 15;
  int lk = (lane >> 4) * 8;
  f32x4 acc[4][4];
  #pragma unroll
  for (int mi = 0; mi < 4; ++mi)
    #pragma unroll
    for (int ni = 0; ni < 4; ++ni) acc[mi][ni] = (f32x4)0.0f;

  #pragma unroll 2
  for (int kb = 0; kb < 8; ++kb) {
    int ko = kb * 32 + lk;
    bf16x8 bh[4], bl[4];
    #pragma unroll
    for (int ni = 0; ni < 4; ++ni) {
      size_t off = (size_t)(cb + ni * 16 + lr) * 256 + ko;
      bh[ni] = *reinterpret_cast<const bf16x8*>(Bhi + off);
      bl[ni] = *reinterpret_cast<const bf16x8*>(Blo + off);
    }
    #pragma unroll
    for (int mi = 0; mi < 4; ++mi) {
      size_t off = (size_t)(rb + mi * 16 + lr) * 256 + ko;   // rows < NP, zero-padded
      bf16x8 ah = *reinterpret_cast<const bf16x8*>(Ahi + off);
      bf16x8 al = *reinterpret_cast<const bf16x8*>(Alo + off);
      #pragma unroll
      for (int ni = 0; ni < 4; ++ni) {
        acc[mi][ni] = __builtin_amdgcn_mfma_f32_16x16x32_bf16(ah, bh[ni], acc[mi][ni], 0, 0, 0);
        acc[mi][ni] = __builtin_amdgcn_mfma_f32_16x16x32_bf16(ah, bl[ni], acc[mi][ni], 0, 0, 0);
        acc[mi][ni] = __builtin_amdgcn_mfma_f32_16x16x32_bf16(al, bh[ni], acc[mi][ni], 0, 0, 0);
      }
    }
  }
  float bias[4];
  #pragma unroll
  for (int ni = 0; ni < 4; ++ni) {
    int j = cb + ni * 16 + lr;
    bias[ni] = bih[j] + bhh[j];
  }
  int orow = (lane >> 4) * 4;
  #pragma unroll
  for (int mi = 0; mi < 4; ++mi)
    #pragma unroll
    for (int ni = 0; ni < 4; ++ni)
      #pragma unroll
      for (int r = 0; r < 4; ++r) {
        int n = rb + mi * 16 + orow + r;
        if (n < N)
          gates[(size_t)n * G + cb + ni * 16 + lr] = acc[mi][ni][r] + bias[ni];
      }
}

// ---------------- LSTM cell (elementwise) ----------------
// h written fp32 (for FC) and as bf16 hi/lo into A-planes cols 128..255.
__global__ void k_cell(const float* __restrict__ gates, float* __restrict__ c,
                       float* __restrict__ h, u16* __restrict__ Ahi,
                       u16* __restrict__ Alo) {
  int idx = blockIdx.x * 256 + threadIdx.x;     // exactly N*H threads
  int n = idx >> 7, ch = idx & 127;
  const float* g = &gates[(size_t)n * G];
  float gi = g[ch], gf = g[128 + ch], gg = g[256 + ch], go = g[384 + ch];
  float si = 1.f / (1.f + expf(-gi));
  float sf = 1.f / (1.f + expf(-gf));
  float so = 1.f / (1.f + expf(-go));
  float tg = tanhf(gg);
  float cn = sf * c[idx] + si * tg;
  c[idx] = cn;
  float hn = so * tanhf(cn);
  h[idx] = hn;
  u16 hh = f2bf(hn);
  size_t base = (size_t)n * 256 + 128 + ch;
  Ahi[base] = hh;
  Alo[base] = f2bf(hn - bf2f(hh));
}

// ---------------- FC per step: out[n][t][:] = h[n] @ W_fc^T + b_fc ----------------
__global__ __launch_bounds__(256, 3) void k_fc(const float* __restrict__ h,
                                               const float* __restrict__ Wfc,
                                               const float* __restrict__ bfc,
                                               float* __restrict__ outp, int t) {
  __shared__ float hsT[128][68];
  __shared__ float wT[128][36];
  int tid = threadIdx.x;
  int n0 = blockIdx.x * 64;
  for (int i = 0; i < 32; ++i) {
    int idx = i * 256 + tid;
    int r = idx >> 7, k = idx & 127;
    hsT[k][r] = (n0 + r < N) ? h[(size_t)(n0 + r) * H + k] : 0.0f;
  }
  for (int i = 0; i < 16; ++i) {
    int idx = i * 256 + tid;          // 4096 = 32*128
    int oc = idx >> 7, k = idx & 127;
    wT[k][oc] = Wfc[idx];
  }
  __syncthreads();
  int og = tid & 15, rg = tid >> 4;   // 16 oc-groups x 16 row-groups
  int oc0 = og * 2, r0 = rg * 4;
  float acc[4][2] = {};
  #pragma unroll 2
  for (int k = 0; k < 128; ++k) {
    float4 a = *(const float4*)&hsT[k][r0];
    float2 w = *(const float2*)&wT[k][oc0];
    float ar[4] = {a.x, a.y, a.z, a.w};
    #pragma unroll
    for (int i = 0; i < 4; ++i) {
      acc[i][0] = fmaf(ar[i], w.x, acc[i][0]);
      acc[i][1] = fmaf(ar[i], w.y, acc[i][1]);
    }
  }
  float b0 = bfc[oc0], b1 = bfc[oc0 + 1];
  #pragma unroll
  for (int i = 0; i < 4; ++i) {
    int n = n0 + r0 + i;
    if (n < N) {
      size_t ob = ((size_t)n * T + t) * OUTD + oc0;
      outp[ob]     = acc[i][0] + b0;
      outp[ob + 1] = acc[i][1] + b1;
    }
  }
}

// ---------------------------------------------------------------------------

extern "C" void kernel_launch(void* const* d_in, const int* in_sizes, int n_in,
                              void* d_out, int out_size, void* d_ws, size_t ws_size,
                              hipStream_t stream) {
  const float* x_seq = (const float*)d_in[0];
  const int*   eidx  = (const int*)d_in[1];
  const int*   erow  = eidx;          // sources
  const int*   ecol  = eidx + E;      // targets
  const float* W_gcn = (const float*)d_in[2];
  const float* b_gcn = (const float*)d_in[3];
  const float* W_ih  = (const float*)d_in[4];
  const float* W_hh  = (const float*)d_in[5];
  const float* b_ih  = (const float*)d_in[6];
  const float* b_hh  = (const float*)d_in[7];
  const float* W_fc  = (const float*)d_in[8];
  const float* b_fc  = (const float*)d_in[9];
  float* outp = (float*)d_out;

  char* base = (char*)d_ws;
  size_t o = 0;
  auto alloc = [&](size_t bytes) -> void* {
    void* p = base + o;
    o += (bytes + 255) & ~(size_t)255;
    return p;
  };
  int*   cnt      = (int*)  alloc((size_t)N * 4);
  int*   cursor   = (int*)  alloc((size_t)N * 4);
  int*   offv     = (int*)  alloc((size_t)(N + 1) * 4);
  int*   csum     = (int*)  alloc((size_t)(NCH + 1) * 4);
  int*   coff     = (int*)  alloc((size_t)(NCH + 1) * 4);
  float* dinv     = (float*)alloc((size_t)N * 4);
  int*   csr_src  = (int*)  alloc((size_t)E * 4);
  float* csr_norm = (float*)alloc((size_t)E * 4);
  u16*   bt_hi    = (u16*)  alloc((size_t)G * 256 * 2);
  u16*   bt_lo    = (u16*)  alloc((size_t)G * 256 * 2);
  u16*   bg_hi    = (u16*)  alloc((size_t)H * H * 2);
  u16*   bg_lo    = (u16*)  alloc((size_t)H * H * 2);
  u16*   a_hi     = (u16*)  alloc((size_t)NP * 256 * 2);   // [emb | h] bf16-hi
  u16*   a_lo     = (u16*)  alloc((size_t)NP * 256 * 2);   // [emb | h] bf16-lo
  float* xw       = (float*)alloc((size_t)N * H * 4);
  float* gates    = (float*)alloc((size_t)N * G * 4);
  float* hbuf     = (float*)alloc((size_t)N * H * 4);
  float* cbuf     = (float*)alloc((size_t)N * H * 4);
  (void)ws_size; (void)in_sizes; (void)n_in; (void)out_size;

  hipMemsetAsync(cnt,    0, (size_t)N * 4, stream);
  hipMemsetAsync(cursor, 0, (size_t)N * 4, stream);
  hipMemsetAsync(cbuf,   0, (size_t)N * H * 4, stream);
  hipMemsetAsync(a_hi,   0, (size_t)NP * 256 * 2, stream);  // h cols + pad rows = 0
  hipMemsetAsync(a_lo,   0, (size_t)NP * 256 * 2, stream);

  k_count<<<E / 256, 256, 0, stream>>>(ecol, cnt);
  k_dinv<<<(N + 255) / 256, 256, 0, stream>>>(cnt, dinv);
  k_chunk_sum<<<NCH, SCAN_CH, 0, stream>>>(cnt, csum);
  k_chunk_scan<<<1, 64, 0, stream>>>(csum, coff);
  k_scan_final<<<NCH, SCAN_CH, 0, stream>>>(cnt, coff, offv);
  k_fill<<<E / 256, 256, 0, stream>>>(erow, ecol, dinv, offv, cursor, csr_src, csr_norm);
  k_wsplit_lstm<<<(G * 256) / 256, 256, 0, stream>>>(W_ih, W_hh, bt_hi, bt_lo);
  k_wsplit_gcn<<<(H * H) / 256, 256, 0, stream>>>(W_gcn, bg_hi, bg_lo);

  int mblocks = NP / 128;                 // 391
  int rblocks = (N + 63) / 64;            // for k_fc
  for (int t = 0; t < T; ++t) {
    const float* xt = x_seq + (size_t)t * N * H;
    k_gcn_mfma<<<mblocks, 256, 0, stream>>>(xt, bg_hi, bg_lo, xw);
    k_agg<<<N / 4, 256, 0, stream>>>(xw, offv, csr_src, csr_norm, dinv, b_gcn, a_hi, a_lo);
    k_gates_mfma<<<dim3(mblocks, 4), 256, 0, stream>>>(a_hi, a_lo, bt_hi, bt_lo,
                                                       b_ih, b_hh, gates);
    k_cell<<<(N * H) / 256, 256, 0, stream>>>(gates, cbuf, hbuf, a_hi, a_lo);
    k_fc<<<rblocks, 256, 0, stream>>>(hbuf, W_fc, b_fc, outp, t);
  }
}

// Round 4
// 2857.608 us; speedup vs baseline: 1.9851x; 1.0725x over previous
//
#include <hip/hip_runtime.h>
#include <cstdint>
#include <cstddef>

// ---------------------------------------------------------------------------
// GCN(1 layer, sym-norm w/ self loops) -> LSTM(1 layer, T=9) -> FC, eval mode
// Round 4: round-3 fusion + ping-pong A planes to fix the h read/write race
// (gates step t reads A[t&1], writes h_t into A[(t+1)&1]).
// ---------------------------------------------------------------------------

constexpr int N    = 50000;
constexpr int NP   = 50048;  // padded to 128-row blocks (391*128)
constexpr int E    = 1600000;
constexpr int T    = 9;
constexpr int H    = 128;    // F_IN == H == 128
constexpr int G    = 512;    // 4*H (gates i,f,g,o)
constexpr int OUTD = 32;

constexpr int SCAN_CH = 512;
constexpr int NCH = (N + SCAN_CH - 1) / SCAN_CH;   // 98

typedef __attribute__((ext_vector_type(8))) short bf16x8;
typedef __attribute__((ext_vector_type(4))) float f32x4;
typedef unsigned short u16;

__device__ __forceinline__ u16 f2bf(float f) {        // RNE f32 -> bf16 bits
  unsigned u = __builtin_bit_cast(unsigned, f);
  u += 0x7fffu + ((u >> 16) & 1u);
  return (u16)(u >> 16);
}
__device__ __forceinline__ float bf2f(u16 h) {
  unsigned u = ((unsigned)h) << 16;
  return __builtin_bit_cast(float, u);
}

// ---------------- degree / CSR build ----------------

__global__ void k_count(const int* __restrict__ col, int* __restrict__ cnt) {
  int e = blockIdx.x * 256 + threadIdx.x;
  if (e < E) atomicAdd(&cnt[col[e]], 1);
}

__global__ void k_dinv(const int* __restrict__ cnt, float* __restrict__ dinv) {
  int v = blockIdx.x * 256 + threadIdx.x;
  if (v < N) dinv[v] = rsqrtf((float)cnt[v] + 1.0f);   // +1 self loop
}

__global__ void k_chunk_sum(const int* __restrict__ cnt, int* __restrict__ csum) {
  __shared__ int sp[SCAN_CH / 64];
  int i = blockIdx.x * SCAN_CH + threadIdx.x;
  int v = (i < N) ? cnt[i] : 0;
  for (int off = 32; off > 0; off >>= 1) v += __shfl_down(v, off, 64);
  if ((threadIdx.x & 63) == 0) sp[threadIdx.x >> 6] = v;
  __syncthreads();
  if (threadIdx.x == 0) {
    int s = 0;
    #pragma unroll
    for (int w = 0; w < SCAN_CH / 64; ++w) s += sp[w];
    csum[blockIdx.x] = s;
  }
}

__global__ void k_chunk_scan(const int* __restrict__ csum, int* __restrict__ coff) {
  if (blockIdx.x == 0 && threadIdx.x == 0) {
    int run = 0;
    for (int b = 0; b < NCH; ++b) { coff[b] = run; run += csum[b]; }
    coff[NCH] = run;
  }
}

__global__ void k_scan_final(const int* __restrict__ cnt, const int* __restrict__ coff,
                             int* __restrict__ offv) {
  __shared__ int s[SCAN_CH];
  int tid = threadIdx.x;
  int i = blockIdx.x * SCAN_CH + tid;
  int v = (i < N) ? cnt[i] : 0;
  s[tid] = v;
  __syncthreads();
  for (int st = 1; st < SCAN_CH; st <<= 1) {
    int tv = (tid >= st) ? s[tid - st] : 0;
    __syncthreads();
    s[tid] += tv;
    __syncthreads();
  }
  if (i < N) offv[i] = coff[blockIdx.x] + s[tid] - v;   // exclusive
  if (blockIdx.x == 0 && tid == 0) offv[N] = coff[NCH];
}

__global__ void k_fill(const int* __restrict__ row, const int* __restrict__ col,
                       const float* __restrict__ dinv, const int* __restrict__ offv,
                       int* __restrict__ cursor, int* __restrict__ csr_src,
                       float* __restrict__ csr_norm) {
  int e = blockIdx.x * 256 + threadIdx.x;
  if (e >= E) return;
  int r = row[e], c = col[e];
  int p = atomicAdd(&cursor[c], 1);
  int idx = offv[c] + p;
  csr_src[idx]  = r;
  csr_norm[idx] = dinv[r] * dinv[c];
}

// ---------------- weight split/transpose (once per call) ----------------
// LSTM: Bt[j][k] (j<512, k<256): k<128 -> W_ih[j][k], else W_hh[j][k-128]
__global__ void k_wsplit_lstm(const float* __restrict__ Wih, const float* __restrict__ Whh,
                              u16* __restrict__ bhi, u16* __restrict__ blo) {
  int idx = blockIdx.x * 256 + threadIdx.x;   // 512*256
  if (idx >= G * 256) return;
  int j = idx >> 8, k = idx & 255;
  float f = (k < H) ? Wih[j * H + k] : Whh[j * H + (k - H)];
  u16 h = f2bf(f);
  u16 l = f2bf(f - bf2f(h));
  bhi[idx] = h; blo[idx] = l;
}

// GCN: Bt[j][k] = W_gcn[k][j]  (128x128)
__global__ void k_wsplit_gcn(const float* __restrict__ Wg,
                             u16* __restrict__ bhi, u16* __restrict__ blo) {
  int idx = blockIdx.x * 256 + threadIdx.x;   // 128*128
  if (idx >= H * H) return;
  int j = idx >> 7, k = idx & 127;
  float f = Wg[k * H + j];
  u16 h = f2bf(f);
  u16 l = f2bf(f - bf2f(h));
  bhi[idx] = h; blo[idx] = l;
}

// ---------------- GCN GEMM (MFMA): xw = x_t @ W_gcn ----------------
// block 256 thr = 4 waves (2x2) -> 128 rows x 128 cols; K=128 (4 kblocks).
__global__ __launch_bounds__(256) void k_gcn_mfma(const float* __restrict__ X,
                                                  const u16* __restrict__ Bhi,
                                                  const u16* __restrict__ Blo,
                                                  float* __restrict__ xw) {
  int lane = threadIdx.x & 63, wid = threadIdx.x >> 6;
  int wr = wid >> 1, wc = wid & 1;
  int rb = blockIdx.x * 128 + wr * 64;
  int cb = wc * 64;
  int lr = lane & 15;
  int lk = (lane >> 4) * 8;
  f32x4 acc[4][4];
  #pragma unroll
  for (int mi = 0; mi < 4; ++mi)
    #pragma unroll
    for (int ni = 0; ni < 4; ++ni) acc[mi][ni] = (f32x4)0.0f;

  #pragma unroll
  for (int kb = 0; kb < 4; ++kb) {
    int ko = kb * 32 + lk;
    bf16x8 bh[4], bl[4];
    #pragma unroll
    for (int ni = 0; ni < 4; ++ni) {
      size_t off = (size_t)(cb + ni * 16 + lr) * H + ko;
      bh[ni] = *reinterpret_cast<const bf16x8*>(Bhi + off);
      bl[ni] = *reinterpret_cast<const bf16x8*>(Blo + off);
    }
    #pragma unroll
    for (int mi = 0; mi < 4; ++mi) {
      int r = rb + mi * 16 + lr;
      r = r < N ? r : N - 1;                     // clamp (pad rows discarded)
      const float* ap = X + (size_t)r * H + ko;
      float4 a0 = *(const float4*)ap;
      float4 a1 = *(const float4*)(ap + 4);
      float fe[8] = {a0.x, a0.y, a0.z, a0.w, a1.x, a1.y, a1.z, a1.w};
      bf16x8 ah, al;
      #pragma unroll
      for (int e = 0; e < 8; ++e) {
        u16 hh = f2bf(fe[e]);
        ah[e] = (short)hh;
        al[e] = (short)f2bf(fe[e] - bf2f(hh));
      }
      #pragma unroll
      for (int ni = 0; ni < 4; ++ni) {
        acc[mi][ni] = __builtin_amdgcn_mfma_f32_16x16x32_bf16(ah, bh[ni], acc[mi][ni], 0, 0, 0);
        acc[mi][ni] = __builtin_amdgcn_mfma_f32_16x16x32_bf16(ah, bl[ni], acc[mi][ni], 0, 0, 0);
        acc[mi][ni] = __builtin_amdgcn_mfma_f32_16x16x32_bf16(al, bh[ni], acc[mi][ni], 0, 0, 0);
      }
    }
  }
  int orow = (lane >> 4) * 4;
  #pragma unroll
  for (int mi = 0; mi < 4; ++mi)
    #pragma unroll
    for (int ni = 0; ni < 4; ++ni)
      #pragma unroll
      for (int r = 0; r < 4; ++r) {
        int n = rb + mi * 16 + orow + r;
        if (n < N) xw[(size_t)n * H + cb + ni * 16 + lr] = acc[mi][ni][r];
      }
}

// ---------------- aggregation -> emb (bf16 hi/lo planes) ----------------
// Wave per vertex; two 32-lane halves process even/odd edges (float4/lane),
// combined via shfl_xor(32). emb written into Ahi/Alo cols 0..127.
__global__ __launch_bounds__(256) void k_agg(const float* __restrict__ xw,
                                             const int* __restrict__ offv,
                                             const int* __restrict__ csr_src,
                                             const float* __restrict__ csr_norm,
                                             const float* __restrict__ dinv,
                                             const float* __restrict__ bg,
                                             u16* __restrict__ Ahi,
                                             u16* __restrict__ Alo) {
  int wid = threadIdx.x >> 6, lane = threadIdx.x & 63;
  int v = blockIdx.x * 4 + wid;          // N % 4 == 0
  int half = lane >> 5, sl = lane & 31;
  int c0 = sl * 4;
  float ax = 0.f, ay = 0.f, az = 0.f, aw = 0.f;
  if (half == 0) {                       // self term once
    float dv = dinv[v];
    float w = dv * dv;
    float4 xs = *(const float4*)&xw[(size_t)v * H + c0];
    ax = xs.x * w; ay = xs.y * w; az = xs.z * w; aw = xs.w * w;
  }
  int e0 = offv[v], e1 = offv[v + 1];
  for (int e = e0 + half; e < e1; e += 2) {
    int s = csr_src[e]; float m = csr_norm[e];
    float4 x = *(const float4*)&xw[(size_t)s * H + c0];
    ax = fmaf(x.x, m, ax); ay = fmaf(x.y, m, ay);
    az = fmaf(x.z, m, az); aw = fmaf(x.w, m, aw);
  }
  ax += __shfl_xor(ax, 32, 64);
  ay += __shfl_xor(ay, 32, 64);
  az += __shfl_xor(az, 32, 64);
  aw += __shfl_xor(aw, 32, 64);
  float4 bb = *(const float4*)&bg[c0];
  float o0 = fmaxf(ax + bb.x, 0.f), o1 = fmaxf(ay + bb.y, 0.f);
  float o2 = fmaxf(az + bb.z, 0.f), o3 = fmaxf(aw + bb.w, 0.f);
  u16 h0 = f2bf(o0), h1 = f2bf(o1), h2 = f2bf(o2), h3 = f2bf(o3);
  size_t base = (size_t)v * 256 + c0;
  if (half == 0) {
    *(ushort4*)&Ahi[base] = make_ushort4(h0, h1, h2, h3);
  } else {
    u16 l0 = f2bf(o0 - bf2f(h0)), l1 = f2bf(o1 - bf2f(h1));
    u16 l2 = f2bf(o2 - bf2f(h2)), l3 = f2bf(o3 - bf2f(h3));
    *(ushort4*)&Alo[base] = make_ushort4(l0, l1, l2, l3);
  }
}

// ---------------- fused gates GEMM + LSTM cell ----------------
// ni spans the 4 gate groups: j = ni*128 + ch, so acc[mi][ni][r] holds
// (i,f,g,o) for the SAME (row, channel) -> cell update in-register.
// Reads A-cur (emb_t | h_{t-1}); writes h_t into A-nxt (ping-pong, no race).
// grid (NP/128, 4); block 256 = 4 waves (wr: row half, wc: channel half).
template<bool FIRST>
__global__ __launch_bounds__(256) void k_gates_cell(const u16* __restrict__ Ahi,
                                                    const u16* __restrict__ Alo,
                                                    const u16* __restrict__ Bhi,
                                                    const u16* __restrict__ Blo,
                                                    const float* __restrict__ bih,
                                                    const float* __restrict__ bhh,
                                                    float* __restrict__ cbuf,
                                                    float* __restrict__ hbuf,
                                                    u16* __restrict__ oAhi,
                                                    u16* __restrict__ oAlo) {
  int lane = threadIdx.x & 63, wid = threadIdx.x >> 6;
  int wr = wid >> 1, wc = wid & 1;
  int rb = blockIdx.x * 128 + wr * 64;
  int chb = blockIdx.y * 32 + wc * 16;
  int lr = lane & 15;
  int lk = (lane >> 4) * 8;
  f32x4 acc[4][4];
  #pragma unroll
  for (int mi = 0; mi < 4; ++mi)
    #pragma unroll
    for (int ni = 0; ni < 4; ++ni) acc[mi][ni] = (f32x4)0.0f;

  const int KB = FIRST ? 4 : 8;          // t=0: h==0, skip upper K half
  #pragma unroll 2
  for (int kb = 0; kb < KB; ++kb) {
    int ko = kb * 32 + lk;
    bf16x8 bh[4], bl[4];
    #pragma unroll
    for (int ni = 0; ni < 4; ++ni) {
      size_t off = (size_t)(ni * 128 + chb + lr) * 256 + ko;
      bh[ni] = *reinterpret_cast<const bf16x8*>(Bhi + off);
      bl[ni] = *reinterpret_cast<const bf16x8*>(Blo + off);
    }
    #pragma unroll
    for (int mi = 0; mi < 4; ++mi) {
      size_t off = (size_t)(rb + mi * 16 + lr) * 256 + ko;
      bf16x8 ah = *reinterpret_cast<const bf16x8*>(Ahi + off);
      bf16x8 al = *reinterpret_cast<const bf16x8*>(Alo + off);
      #pragma unroll
      for (int ni = 0; ni < 4; ++ni) {
        acc[mi][ni] = __builtin_amdgcn_mfma_f32_16x16x32_bf16(ah, bh[ni], acc[mi][ni], 0, 0, 0);
        acc[mi][ni] = __builtin_amdgcn_mfma_f32_16x16x32_bf16(ah, bl[ni], acc[mi][ni], 0, 0, 0);
        acc[mi][ni] = __builtin_amdgcn_mfma_f32_16x16x32_bf16(al, bh[ni], acc[mi][ni], 0, 0, 0);
      }
    }
  }
  int ch = chb + lr;
  float bias[4];
  #pragma unroll
  for (int ni = 0; ni < 4; ++ni) {
    int j = ni * 128 + ch;
    bias[ni] = bih[j] + bhh[j];
  }
  int orow = (lane >> 4) * 4;
  #pragma unroll
  for (int mi = 0; mi < 4; ++mi) {
    #pragma unroll
    for (int r = 0; r < 4; ++r) {
      int n = rb + mi * 16 + orow + r;
      if (n >= N) continue;
      float gi = acc[mi][0][r] + bias[0];
      float gf = acc[mi][1][r] + bias[1];
      float gg = acc[mi][2][r] + bias[2];
      float go = acc[mi][3][r] + bias[3];
      float si = 1.f / (1.f + expf(-gi));
      float sf = 1.f / (1.f + expf(-gf));
      float so = 1.f / (1.f + expf(-go));
      float tg = tanhf(gg);
      size_t ci = (size_t)n * H + ch;
      float cn = FIRST ? si * tg : fmaf(sf, cbuf[ci], si * tg);
      cbuf[ci] = cn;
      float hn = so * tanhf(cn);
      hbuf[ci] = hn;
      u16 hh = f2bf(hn);
      size_t ab = (size_t)n * 256 + 128 + ch;
      oAhi[ab] = hh;
      oAlo[ab] = f2bf(hn - bf2f(hh));
    }
  }
}

// ---------------- FC per step: out[n][t][:] = h[n] @ W_fc^T + b_fc ----------------
__global__ __launch_bounds__(256, 3) void k_fc(const float* __restrict__ h,
                                               const float* __restrict__ Wfc,
                                               const float* __restrict__ bfc,
                                               float* __restrict__ outp, int t) {
  __shared__ float hsT[128][68];
  __shared__ float wT[128][36];
  int tid = threadIdx.x;
  int n0 = blockIdx.x * 64;
  for (int i = 0; i < 32; ++i) {
    int idx = i * 256 + tid;
    int r = idx >> 7, k = idx & 127;
    hsT[k][r] = (n0 + r < N) ? h[(size_t)(n0 + r) * H + k] : 0.0f;
  }
  for (int i = 0; i < 16; ++i) {
    int idx = i * 256 + tid;          // 4096 = 32*128
    int oc = idx >> 7, k = idx & 127;
    wT[k][oc] = Wfc[idx];
  }
  __syncthreads();
  int og = tid & 15, rg = tid >> 4;   // 16 oc-groups x 16 row-groups
  int oc0 = og * 2, r0 = rg * 4;
  float acc[4][2] = {};
  #pragma unroll 2
  for (int k = 0; k < 128; ++k) {
    float4 a = *(const float4*)&hsT[k][r0];
    float2 w = *(const float2*)&wT[k][oc0];
    float ar[4] = {a.x, a.y, a.z, a.w};
    #pragma unroll
    for (int i = 0; i < 4; ++i) {
      acc[i][0] = fmaf(ar[i], w.x, acc[i][0]);
      acc[i][1] = fmaf(ar[i], w.y, acc[i][1]);
    }
  }
  float b0 = bfc[oc0], b1 = bfc[oc0 + 1];
  #pragma unroll
  for (int i = 0; i < 4; ++i) {
    int n = n0 + r0 + i;
    if (n < N) {
      size_t ob = ((size_t)n * T + t) * OUTD + oc0;
      outp[ob]     = acc[i][0] + b0;
      outp[ob + 1] = acc[i][1] + b1;
    }
  }
}

// ---------------------------------------------------------------------------

extern "C" void kernel_launch(void* const* d_in, const int* in_sizes, int n_in,
                              void* d_out, int out_size, void* d_ws, size_t ws_size,
                              hipStream_t stream) {
  const float* x_seq = (const float*)d_in[0];
  const int*   eidx  = (const int*)d_in[1];
  const int*   erow  = eidx;          // sources
  const int*   ecol  = eidx + E;      // targets
  const float* W_gcn = (const float*)d_in[2];
  const float* b_gcn = (const float*)d_in[3];
  const float* W_ih  = (const float*)d_in[4];
  const float* W_hh  = (const float*)d_in[5];
  const float* b_ih  = (const float*)d_in[6];
  const float* b_hh  = (const float*)d_in[7];
  const float* W_fc  = (const float*)d_in[8];
  const float* b_fc  = (const float*)d_in[9];
  float* outp = (float*)d_out;

  char* base = (char*)d_ws;
  size_t o = 0;
  auto alloc = [&](size_t bytes) -> void* {
    void* p = base + o;
    o += (bytes + 255) & ~(size_t)255;
    return p;
  };
  int*   cnt      = (int*)  alloc((size_t)N * 4);
  int*   cursor   = (int*)  alloc((size_t)N * 4);
  int*   offv     = (int*)  alloc((size_t)(N + 1) * 4);
  int*   csum     = (int*)  alloc((size_t)(NCH + 1) * 4);
  int*   coff     = (int*)  alloc((size_t)(NCH + 1) * 4);
  float* dinv     = (float*)alloc((size_t)N * 4);
  int*   csr_src  = (int*)  alloc((size_t)E * 4);
  float* csr_norm = (float*)alloc((size_t)E * 4);
  u16*   bt_hi    = (u16*)  alloc((size_t)G * 256 * 2);
  u16*   bt_lo    = (u16*)  alloc((size_t)G * 256 * 2);
  u16*   bg_hi    = (u16*)  alloc((size_t)H * H * 2);
  u16*   bg_lo    = (u16*)  alloc((size_t)H * H * 2);
  u16*   a_hi0    = (u16*)  alloc((size_t)NP * 256 * 2);   // [emb | h] bf16-hi, even t
  u16*   a_lo0    = (u16*)  alloc((size_t)NP * 256 * 2);
  u16*   a_hi1    = (u16*)  alloc((size_t)NP * 256 * 2);   // odd t
  u16*   a_lo1    = (u16*)  alloc((size_t)NP * 256 * 2);
  float* xw       = (float*)alloc((size_t)N * H * 4);
  float* hbuf     = (float*)alloc((size_t)N * H * 4);
  float* cbuf     = (float*)alloc((size_t)N * H * 4);
  (void)ws_size; (void)in_sizes; (void)n_in; (void)out_size;

  u16* AHI[2] = {a_hi0, a_hi1};
  u16* ALO[2] = {a_lo0, a_lo1};

  // only the small CSR counters need zeroing; h/c state handled by the
  // FIRST-step specialization; pad rows only affect discarded output rows.
  hipMemsetAsync(cnt,    0, (size_t)N * 4, stream);
  hipMemsetAsync(cursor, 0, (size_t)N * 4, stream);

  k_count<<<E / 256, 256, 0, stream>>>(ecol, cnt);
  k_dinv<<<(N + 255) / 256, 256, 0, stream>>>(cnt, dinv);
  k_chunk_sum<<<NCH, SCAN_CH, 0, stream>>>(cnt, csum);
  k_chunk_scan<<<1, 64, 0, stream>>>(csum, coff);
  k_scan_final<<<NCH, SCAN_CH, 0, stream>>>(cnt, coff, offv);
  k_fill<<<E / 256, 256, 0, stream>>>(erow, ecol, dinv, offv, cursor, csr_src, csr_norm);
  k_wsplit_lstm<<<(G * 256) / 256, 256, 0, stream>>>(W_ih, W_hh, bt_hi, bt_lo);
  k_wsplit_gcn<<<(H * H) / 256, 256, 0, stream>>>(W_gcn, bg_hi, bg_lo);

  int mblocks = NP / 128;                 // 391
  int rblocks = (N + 63) / 64;            // for k_fc
  for (int t = 0; t < T; ++t) {
    int cur = t & 1, nxt = cur ^ 1;
    const float* xt = x_seq + (size_t)t * N * H;
    k_gcn_mfma<<<mblocks, 256, 0, stream>>>(xt, bg_hi, bg_lo, xw);
    k_agg<<<N / 4, 256, 0, stream>>>(xw, offv, csr_src, csr_norm, dinv, b_gcn,
                                     AHI[cur], ALO[cur]);
    if (t == 0)
      k_gates_cell<true><<<dim3(mblocks, 4), 256, 0, stream>>>(
          AHI[cur], ALO[cur], bt_hi, bt_lo, b_ih, b_hh, cbuf, hbuf, AHI[nxt], ALO[nxt]);
    else
      k_gates_cell<false><<<dim3(mblocks, 4), 256, 0, stream>>>(
          AHI[cur], ALO[cur], bt_hi, bt_lo, b_ih, b_hh, cbuf, hbuf, AHI[nxt], ALO[nxt]);
    k_fc<<<rblocks, 256, 0, stream>>>(hbuf, W_fc, b_fc, outp, t);
  }
}